// Round 5
// baseline (247.197 us; speedup 1.0000x reference)
//
#include <hip/hip_runtime.h>
#include <hip/hip_bf16.h>

// Problem dims (fixed by reference)
#define B_    8
#define C_    512
#define HW_   1024     // H*W = 32*32
#define NG    32
#define GCH   16
#define EPSV  1e-6f

typedef __attribute__((ext_vector_type(8))) short short8;   // 8 bf16 (4 VGPRs)
typedef __attribute__((ext_vector_type(4))) short short4v;  // 4 bf16
typedef __attribute__((ext_vector_type(4))) float floatx4;  // MFMA C/D

static __device__ __forceinline__ short f2bs(float f) {
  return __builtin_bit_cast(short, __float2bfloat16(f));
}
static __device__ __forceinline__ short4v pack4(float a, float b, float c, float d) {
  return (short4v){f2bs(a), f2bs(b), f2bs(c), f2bs(d)};
}
#define MFMA(a, b, c) __builtin_amdgcn_mfma_f32_16x16x32_bf16((a), (b), (c), 0, 0, 0)

// ---------------------------------------------------------------------------
// fp32 -> bf16 cast (weights); 4 elems/thread
// ---------------------------------------------------------------------------
__global__ __launch_bounds__(256) void cast_f2b(const float* __restrict__ s,
                                                short* __restrict__ d) {
  int i = blockIdx.x * 256 + threadIdx.x;
  float4 v = reinterpret_cast<const float4*>(s)[i];
  reinterpret_cast<short4v*>(d)[i] = pack4(v.x, v.y, v.z, v.w);
}

// ---------------------------------------------------------------------------
// Kernel 1a: GroupNorm stats.  One block per (b, group) -> {mean, rsig}.
// ---------------------------------------------------------------------------
__global__ __launch_bounds__(256) void gn_stats(
    const float* __restrict__ x, float2* __restrict__ stats) {
  int bg = blockIdx.x;
  const int n = GCH * HW_;       // 16384
  const float* xp = x + (size_t)bg * n;
  int t = threadIdx.x;

  float s = 0.f, ss = 0.f;
  for (int i = t; i < n / 4; i += 256) {   // i indexes float4s
    float4 v = *reinterpret_cast<const float4*>(xp + i * 4);
    s  += (v.x + v.y) + (v.z + v.w);
    ss += (v.x * v.x + v.y * v.y) + (v.z * v.z + v.w * v.w);
  }
  for (int o = 32; o > 0; o >>= 1) {
    s  += __shfl_down(s, o);
    ss += __shfl_down(ss, o);
  }
  __shared__ float rs_[4], rss_[4];
  int wid = t >> 6, lane = t & 63;
  if (lane == 0) { rs_[wid] = s; rss_[wid] = ss; }
  __syncthreads();
  if (t == 0) {
    float stot  = rs_[0] + rs_[1] + rs_[2] + rs_[3];
    float sstot = rss_[0] + rss_[1] + rss_[2] + rss_[3];
    float mean = stot / (float)n;
    float var  = sstot / (float)n - mean * mean;
    stats[bg] = make_float2(mean, rsqrtf(var + EPSV));
  }
}

// ---------------------------------------------------------------------------
// Kernel 1b: normalize + transpose -> ht[b][seq][ch] bf16.
// ---------------------------------------------------------------------------
__global__ __launch_bounds__(256) void gn_apply(
    const float* __restrict__ x, const float2* __restrict__ stats,
    const float* __restrict__ gamma, const float* __restrict__ beta,
    short* __restrict__ ht) {
  __shared__ float Ls[64 * 65];
  int s0 = blockIdx.x * 64, ch0 = blockIdx.y * 64, b = blockIdx.z;
  int t = threadIdx.x;

  for (int i = 0; i < 4; i++) {
    int lin = t + i * 256;           // 64 rows x 16 float4
    int r = lin >> 4, c4 = lin & 15;
    int ch = ch0 + r;
    float2 st = stats[b * NG + (ch >> 4)];
    float ga = gamma[ch] * st.y;     // fold rsig into gamma
    float be = beta[ch] - st.x * ga;
    float4 v = *reinterpret_cast<const float4*>(
        x + ((size_t)(b * C_ + ch)) * HW_ + s0 + c4 * 4);
    Ls[r * 65 + c4 * 4 + 0] = v.x * ga + be;
    Ls[r * 65 + c4 * 4 + 1] = v.y * ga + be;
    Ls[r * 65 + c4 * 4 + 2] = v.z * ga + be;
    Ls[r * 65 + c4 * 4 + 3] = v.w * ga + be;
  }
  __syncthreads();
  for (int i = 0; i < 4; i++) {
    int lin = t + i * 256;           // 64 seq x 16 short4
    int sq = lin >> 4, cq = lin & 15;
    float a0 = Ls[(cq * 4 + 0) * 65 + sq];
    float a1 = Ls[(cq * 4 + 1) * 65 + sq];
    float a2 = Ls[(cq * 4 + 2) * 65 + sq];
    float a3 = Ls[(cq * 4 + 3) * 65 + sq];
    *reinterpret_cast<short4v*>(
        ht + ((size_t)b * 1024 + s0 + sq) * 512 + ch0 + cq * 4) =
        pack4(a0, a1, a2, a3);
  }
}

// ---------------------------------------------------------------------------
// Kernel 2: LDS-free MFMA QKV GEMM.
//   Q scale = 0.125 * log2(e): attn softmax then uses exp2 directly.
// ---------------------------------------------------------------------------
__global__ __launch_bounds__(256) void gemm_qkv(
    const short* __restrict__ Wb, const short* __restrict__ ht,
    const float* __restrict__ bias,
    short* __restrict__ Qt, short* __restrict__ Kt, short* __restrict__ Vn) {
  int bx = blockIdx.x, by = blockIdx.y, bb = blockIdx.z;
  int m0 = by * 128, n0 = bx * 128;
  int t = threadIdx.x;
  int w = t >> 6, lane = t & 63, n16 = lane & 15, quad = lane >> 4;
  int wm = (w >> 1) * 64, wn = (w & 1) * 64;

  const short* Ab[4];
  const short* Bb[4];
  for (int im = 0; im < 4; im++)
    Ab[im] = Wb + (size_t)(m0 + wm + im * 16 + n16) * 512 + quad * 8;
  const short* Xb = ht + (size_t)bb * 1024 * 512;
  for (int in = 0; in < 4; in++)
    Bb[in] = Xb + (size_t)(n0 + wn + in * 16 + n16) * 512 + quad * 8;

  floatx4 acc[4][4];
  for (int i = 0; i < 4; i++)
    for (int j = 0; j < 4; j++) acc[i][j] = (floatx4){0.f, 0.f, 0.f, 0.f};

#pragma unroll 2
  for (int kk = 0; kk < 512; kk += 32) {
    short8 a[4], b[4];
    for (int im = 0; im < 4; im++)
      a[im] = *reinterpret_cast<const short8*>(Ab[im] + kk);
    for (int in = 0; in < 4; in++)
      b[in] = *reinterpret_cast<const short8*>(Bb[in] + kk);
    for (int im = 0; im < 4; im++)
      for (int in = 0; in < 4; in++)
        acc[im][in] = MFMA(a[im], b[in], acc[im][in]);
  }

  if (m0 < 1024) {                 // Q or K: transposed store [seq][d]
    const bool isQ = (m0 < 512);
    short* base = isQ ? Qt : Kt;
    // Q: fold 1/sqrt(64) AND log2(e) so attn uses exp2:  0.125*1.44269504
    const float sc = isQ ? 0.18033688f : 1.0f;
    for (int im = 0; im < 4; im++) {
      int m = m0 + wm + im * 16 + quad * 4;
      int hh = (m >> 6) & 7, d0 = m & 63;
      float4 bi = *reinterpret_cast<const float4*>(&bias[m]);
      short* hb = base + (size_t)(bb * 8 + hh) * 1024 * 64 + d0;
      for (int in = 0; in < 4; in++) {
        int nn = n0 + wn + in * 16 + n16;
        *reinterpret_cast<short4v*>(hb + (size_t)nn * 64) =
            pack4((acc[im][in][0] + bi.x) * sc, (acc[im][in][1] + bi.y) * sc,
                  (acc[im][in][2] + bi.z) * sc, (acc[im][in][3] + bi.w) * sc);
      }
    }
  } else {                         // V: natural store [ch][seq]
    for (int im = 0; im < 4; im++) {
      int m = m0 + wm + im * 16 + quad * 4;
      float4 bi = *reinterpret_cast<const float4*>(&bias[m]);
      int ch = m - 1024;
      for (int in = 0; in < 4; in++) {
        int nn = n0 + wn + in * 16 + n16;
        short* vp = Vn + (size_t)(bb * 512 + ch) * 1024 + nn;
        vp[0]    = f2bs(acc[im][in][0] + bi.x);
        vp[1024] = f2bs(acc[im][in][1] + bi.y);
        vp[2048] = f2bs(acc[im][in][2] + bi.z);
        vp[3072] = f2bs(acc[im][in][3] + bi.w);
      }
    }
  }
}

// ---------------------------------------------------------------------------
// Kernel 3: barrier-free MFMA attention, v5: cross-kt software pipeline.
//   r3 post-mortem: memory fixes (L2-resident K/V, dbuf, early V) changed
//   NOTHING (67.0 -> 66.8 us) => critical path is the per-iteration serial
//   chain QK->expf->cvt->ds_write->drain->ds_read->PV with 2 lockstep
//   waves/SIMD.  Fix: compute S(kt+1)=QK(kt+1) BETWEEN the P-writes and
//   P-reads of iteration kt (independent MFMA work fills the VALU/LDS
//   window).  Two S buffers role-swapped by a 2-step unroll (static idx).
//   At this grid (2 blocks/CU) VGPR<=256 is occupancy-free (r1 lesson:
//   never force 4 waves/SIMD here).  XCD remap kept (proven: FETCH 70->12MB).
//   exp2f (NOT __exp2f: glibc macro collision, r4 build failure) lowers to
//   the native v_exp_f32 (hardware exp IS base-2).
// ---------------------------------------------------------------------------
__global__ __launch_bounds__(256, 2) void attn_mfma(
    const short* __restrict__ Qt, const short* __restrict__ Kt,
    const short* __restrict__ Vn, short* __restrict__ attnT) {
  __shared__ short Ps[4][2][2][1024];   // [wave][kt&1][qt][16*64]  32 KB
  int blk0 = blockIdx.x;
  int blk = (blk0 & 7) * 64 + (blk0 >> 3);   // 512 = 8 XCD x 64: batch->XCD
  int qb = blk & 7, h = (blk >> 3) & 7, b = blk >> 6;
  int t = threadIdx.x;
  int w = t >> 6, lane = t & 63, n16 = lane & 15, quad = lane >> 4;
  int q0 = qb * 128 + w * 32;

  const short* Qp = Qt + (size_t)(b * 8 + h) * 1024 * 64;
  const short* Kp = Kt + (size_t)(b * 8 + h) * 1024 * 64;
  const short* Vp = Vn + (size_t)(b * 512 + h * 64) * 1024;

  short8 qa[2][2];
  for (int qt = 0; qt < 2; qt++)
    for (int f = 0; f < 2; f++)
      qa[qt][f] = *reinterpret_cast<const short8*>(
          Qp + (size_t)(q0 + qt * 16 + n16) * 64 + f * 32 + quad * 8);

  floatx4 O[2][4];
  float l[2][4];
  for (int qt = 0; qt < 2; qt++)
    for (int i = 0; i < 4; i++) {
      O[qt][i] = (floatx4){0.f, 0.f, 0.f, 0.f};
      l[qt][i] = 0.f;
    }

  short8 kfB[4][2];   // single rotating K buffer (consumed then re-loaded)

#define LOADK(ktv)                                                           \
  do {                                                                       \
    int kk0_ = (ktv) * 64;                                                   \
    for (int nt_ = 0; nt_ < 4; nt_++)                                        \
      for (int f_ = 0; f_ < 2; f_++)                                         \
        kfB[nt_][f_] = *reinterpret_cast<const short8*>(                     \
            Kp + (size_t)(kk0_ + nt_ * 16 + n16) * 64 + f_ * 32 + quad * 8); \
  } while (0)

#define QKSTEP(Sd0, Sd1)                                                     \
  do {                                                                       \
    for (int nt_ = 0; nt_ < 4; nt_++) {                                      \
      floatx4 sa_ = (floatx4){0.f, 0.f, 0.f, 0.f};                           \
      sa_ = MFMA(qa[0][0], kfB[nt_][0], sa_);                                \
      Sd0[nt_] = MFMA(qa[0][1], kfB[nt_][1], sa_);                           \
    }                                                                        \
    for (int nt_ = 0; nt_ < 4; nt_++) {                                      \
      floatx4 sb_ = (floatx4){0.f, 0.f, 0.f, 0.f};                           \
      sb_ = MFMA(qa[1][0], kfB[nt_][0], sb_);                                \
      Sd1[nt_] = MFMA(qa[1][1], kfB[nt_][1], sb_);                           \
    }                                                                        \
  } while (0)

  // STEP(ktv): softmax S_cur(kt) -> P LDS; QK(kt+1) into S_nxt fills the
  // drain window; reload kfB <- K(kt+2); then pa read + PV(kt).
#define STEP(Sc0, Sc1, Sn0, Sn1, ktv)                                        \
  do {                                                                       \
    int k0_ = (ktv) * 64;                                                    \
    short8 v_[4][2];                                                         \
    for (int nd_ = 0; nd_ < 4; nd_++) {                                      \
      const short* vs_ =                                                     \
          Vp + (size_t)(nd_ * 16 + n16) * 1024 + k0_ + quad * 8;             \
      v_[nd_][0] = *reinterpret_cast<const short8*>(vs_);                    \
      v_[nd_][1] = *reinterpret_cast<const short8*>(vs_ + 32);               \
    }                                                                        \
    short* Pb_ = &Ps[w][(ktv) & 1][0][0];                                    \
    int sub_ = n16 & 7, hi_ = n16 >> 3;                                      \
    for (int r_ = 0; r_ < 4; r_++) {                                         \
      int row_ = quad * 4 + r_;                                              \
      float p0_ = exp2f(Sc0[0][r_]);                                         \
      float p1_ = exp2f(Sc0[1][r_]);                                         \
      float p2_ = exp2f(Sc0[2][r_]);                                         \
      float p3_ = exp2f(Sc0[3][r_]);                                         \
      l[0][r_] += (p0_ + p1_) + (p2_ + p3_);                                 \
      Pb_[row_ * 64 + ((0 + hi_ + row_) & 7) * 8 + sub_] = f2bs(p0_);        \
      Pb_[row_ * 64 + ((2 + hi_ + row_) & 7) * 8 + sub_] = f2bs(p1_);        \
      Pb_[row_ * 64 + ((4 + hi_ + row_) & 7) * 8 + sub_] = f2bs(p2_);        \
      Pb_[row_ * 64 + ((6 + hi_ + row_) & 7) * 8 + sub_] = f2bs(p3_);        \
    }                                                                        \
    for (int r_ = 0; r_ < 4; r_++) {                                         \
      int row_ = quad * 4 + r_;                                              \
      float p0_ = exp2f(Sc1[0][r_]);                                         \
      float p1_ = exp2f(Sc1[1][r_]);                                         \
      float p2_ = exp2f(Sc1[2][r_]);                                         \
      float p3_ = exp2f(Sc1[3][r_]);                                         \
      l[1][r_] += (p0_ + p1_) + (p2_ + p3_);                                 \
      Pb_[1024 + row_ * 64 + ((0 + hi_ + row_) & 7) * 8 + sub_] = f2bs(p0_); \
      Pb_[1024 + row_ * 64 + ((2 + hi_ + row_) & 7) * 8 + sub_] = f2bs(p1_); \
      Pb_[1024 + row_ * 64 + ((4 + hi_ + row_) & 7) * 8 + sub_] = f2bs(p2_); \
      Pb_[1024 + row_ * 64 + ((6 + hi_ + row_) & 7) * 8 + sub_] = f2bs(p3_); \
    }                                                                        \
    /* independent next-tile QK: fills expf/LDS-drain stall */               \
    QKSTEP(Sn0, Sn1);                                                        \
    LOADK(((ktv) + 2 < 16) ? (ktv) + 2 : 15);                                \
    short8 pa0_[2], pa1_[2];                                                 \
    for (int f_ = 0; f_ < 2; f_++) {                                         \
      pa0_[f_] = *reinterpret_cast<const short8*>(                           \
          Pb_ + n16 * 64 + ((quad + 4 * f_ + n16) & 7) * 8);                 \
      pa1_[f_] = *reinterpret_cast<const short8*>(                           \
          Pb_ + 1024 + n16 * 64 + ((quad + 4 * f_ + n16) & 7) * 8);          \
    }                                                                        \
    __builtin_amdgcn_s_setprio(1);                                           \
    for (int nd_ = 0; nd_ < 4; nd_++) {                                      \
      O[0][nd_] = MFMA(pa0_[0], v_[nd_][0], O[0][nd_]);                      \
      O[0][nd_] = MFMA(pa0_[1], v_[nd_][1], O[0][nd_]);                      \
      O[1][nd_] = MFMA(pa1_[0], v_[nd_][0], O[1][nd_]);                      \
      O[1][nd_] = MFMA(pa1_[1], v_[nd_][1], O[1][nd_]);                      \
    }                                                                        \
    __builtin_amdgcn_s_setprio(0);                                           \
  } while (0)

  floatx4 SA0[4], SA1[4], SB0[4], SB1[4];
  LOADK(0);
  QKSTEP(SA0, SA1);   // S(0)
  LOADK(1);
#pragma unroll 1
  for (int kt = 0; kt < 16; kt += 2) {
    STEP(SA0, SA1, SB0, SB1, kt);
    STEP(SB0, SB1, SA0, SA1, kt + 1);
  }
#undef STEP
#undef QKSTEP
#undef LOADK

  // epilogue: reduce l across the 16-lane row group, write [seq][ch] bf16
  for (int qt = 0; qt < 2; qt++)
    for (int r = 0; r < 4; r++) {
      float s = l[qt][r];
      s += __shfl_xor(s, 1);
      s += __shfl_xor(s, 2);
      s += __shfl_xor(s, 4);
      s += __shfl_xor(s, 8);
      l[qt][r] = 1.0f / s;
    }
  for (int qt = 0; qt < 2; qt++)
    for (int nd = 0; nd < 4; nd++)
      for (int r = 0; r < 4; r++) {
        int q = q0 + qt * 16 + quad * 4 + r;
        int ch = h * 64 + nd * 16 + n16;
        attnT[((size_t)b * 1024 + q) * 512 + ch] = f2bs(O[qt][nd][r] * l[qt][r]);
      }
}

// ---------------------------------------------------------------------------
// Kernel 4: LDS-free projection GEMM + bias + residual, fp32 out.
// ---------------------------------------------------------------------------
__global__ __launch_bounds__(256) void gemm_out(
    const short* __restrict__ Wb, const short* __restrict__ Xt,
    const float* __restrict__ bias, const float* __restrict__ resid,
    float* __restrict__ out) {
  int bx = blockIdx.x, by = blockIdx.y, bb = blockIdx.z;
  int m0 = by * 128, n0 = bx * 128;
  int t = threadIdx.x;
  int w = t >> 6, lane = t & 63, n16 = lane & 15, quad = lane >> 4;
  int wm = (w >> 1) * 64, wn = (w & 1) * 64;

  const short* Ab[4];
  const short* Bb[4];
  for (int im = 0; im < 4; im++)
    Ab[im] = Wb + (size_t)(m0 + wm + im * 16 + n16) * 512 + quad * 8;
  const short* Xb = Xt + (size_t)bb * 1024 * 512;
  for (int in = 0; in < 4; in++)
    Bb[in] = Xb + (size_t)(n0 + wn + in * 16 + n16) * 512 + quad * 8;

  floatx4 acc[4][4];
  for (int i = 0; i < 4; i++)
    for (int j = 0; j < 4; j++) acc[i][j] = (floatx4){0.f, 0.f, 0.f, 0.f};

#pragma unroll 2
  for (int kk = 0; kk < 512; kk += 32) {
    short8 a[4], b[4];
    for (int im = 0; im < 4; im++)
      a[im] = *reinterpret_cast<const short8*>(Ab[im] + kk);
    for (int in = 0; in < 4; in++)
      b[in] = *reinterpret_cast<const short8*>(Bb[in] + kk);
    for (int im = 0; im < 4; im++)
      for (int in = 0; in < 4; in++)
        acc[im][in] = MFMA(a[im], b[in], acc[im][in]);
  }

  for (int im = 0; im < 4; im++) {
    int m = m0 + wm + im * 16 + quad * 4;
    float4 bi = *reinterpret_cast<const float4*>(&bias[m]);
    for (int in = 0; in < 4; in++) {
      int nn = n0 + wn + in * 16 + n16;
      size_t idx = ((size_t)bb * 512 + m) * 1024 + nn;
      out[idx]        = acc[im][in][0] + bi.x + resid[idx];
      out[idx + 1024] = acc[im][in][1] + bi.y + resid[idx + 1024];
      out[idx + 2048] = acc[im][in][2] + bi.z + resid[idx + 2048];
      out[idx + 3072] = acc[im][in][3] + bi.w + resid[idx + 3072];
    }
  }
}

// ---------------------------------------------------------------------------
extern "C" void kernel_launch(void* const* d_in, const int* in_sizes, int n_in,
                              void* d_out, int out_size, void* d_ws, size_t ws_size,
                              hipStream_t stream) {
  const float* x     = (const float*)d_in[0];
  const float* gamma = (const float*)d_in[1];
  const float* beta  = (const float*)d_in[2];
  const float* w_in  = (const float*)d_in[3];
  const float* b_in  = (const float*)d_in[4];
  const float* w_out = (const float*)d_in[5];
  const float* b_out = (const float*)d_in[6];
  float* out = (float*)d_out;

  char* ws = (char*)d_ws;
  short* ht    = (short*)ws;                    //  8 MiB [8][1024][512]
  short* Qt    = (short*)(ws + (8u  << 20));    //  8 MiB [64][1024][64]
  short* Kt    = (short*)(ws + (16u << 20));    //  8 MiB [64][1024][64]
  short* Vn    = (short*)(ws + (24u << 20));    //  8 MiB [8][512][1024]
  short* attnT = (short*)(ws + (32u << 20));    //  8 MiB [8][1024][512]
  short* wbf1  = (short*)(ws + (40u << 20));    //  1.5 MiB
  short* wbf2  = (short*)(ws + (42u << 20));    //  0.5 MiB
  float2* stats = (float2*)(ws + (44u << 20));  //  2 KiB [256]

  cast_f2b<<<(1536 * 512) / 1024, 256, 0, stream>>>(w_in, wbf1);
  cast_f2b<<<(512 * 512) / 1024, 256, 0, stream>>>(w_out, wbf2);
  gn_stats<<<B_ * NG, 256, 0, stream>>>(x, stats);
  gn_apply<<<dim3(16, 8, B_), 256, 0, stream>>>(x, stats, gamma, beta, ht);
  gemm_qkv<<<dim3(8, 12, B_), 256, 0, stream>>>(wbf1, ht, b_in, Qt, Kt, Vn);
  attn_mfma<<<B_ * 8 * 8, 256, 0, stream>>>(Qt, Kt, Vn, attnT);
  gemm_out<<<dim3(8, 4, B_), 256, 0, stream>>>(wbf2, attnT, b_out, x, out);
}

// Round 6
// 193.415 us; speedup vs baseline: 1.2781x; 1.2781x over previous
//
#include <hip/hip_runtime.h>
#include <hip/hip_bf16.h>

// Problem dims (fixed by reference)
#define B_    8
#define C_    512
#define HW_   1024     // H*W = 32*32
#define NG    32
#define GCH   16
#define EPSV  1e-6f

typedef __attribute__((ext_vector_type(8))) short short8;   // 8 bf16 (4 VGPRs)
typedef __attribute__((ext_vector_type(4))) short short4v;  // 4 bf16
typedef __attribute__((ext_vector_type(4))) float floatx4;  // MFMA C/D

static __device__ __forceinline__ short f2bs(float f) {
  return __builtin_bit_cast(short, __float2bfloat16(f));
}
static __device__ __forceinline__ short4v pack4(float a, float b, float c, float d) {
  return (short4v){f2bs(a), f2bs(b), f2bs(c), f2bs(d)};
}
#define MFMA(a, b, c) __builtin_amdgcn_mfma_f32_16x16x32_bf16((a), (b), (c), 0, 0, 0)

// async global->LDS, 16 B per lane (global_load_lds_dwordx4)
static __device__ __forceinline__ void glds16(const short* g, short* l) {
  __builtin_amdgcn_global_load_lds(
      (const __attribute__((address_space(1))) void*)g,
      (__attribute__((address_space(3))) void*)l, 16, 0, 0);
}

// ---------------------------------------------------------------------------
// fp32 -> bf16 cast for BOTH weight tensors in one launch (saves a dispatch).
// w_in: 196608 float4s, w_out: 65536 float4s; grid 1024 x 256 covers exactly.
// ---------------------------------------------------------------------------
__global__ __launch_bounds__(256) void cast2_f2b(
    const float* __restrict__ s1, short* __restrict__ d1,
    const float* __restrict__ s2, short* __restrict__ d2) {
  int i = blockIdx.x * 256 + threadIdx.x;
  const float* s; short* d; int j;
  if (i < 196608) { s = s1; d = d1; j = i; }
  else            { s = s2; d = d2; j = i - 196608; }
  float4 v = reinterpret_cast<const float4*>(s)[j];
  reinterpret_cast<short4v*>(d)[j] = pack4(v.x, v.y, v.z, v.w);
}

// ---------------------------------------------------------------------------
// Kernel 1a: GroupNorm stats.  One block per (b, group) -> {mean, rsig}.
// ---------------------------------------------------------------------------
__global__ __launch_bounds__(256) void gn_stats(
    const float* __restrict__ x, float2* __restrict__ stats) {
  int bg = blockIdx.x;
  const int n = GCH * HW_;       // 16384
  const float* xp = x + (size_t)bg * n;
  int t = threadIdx.x;

  float s = 0.f, ss = 0.f;
  for (int i = t; i < n / 4; i += 256) {   // i indexes float4s
    float4 v = *reinterpret_cast<const float4*>(xp + i * 4);
    s  += (v.x + v.y) + (v.z + v.w);
    ss += (v.x * v.x + v.y * v.y) + (v.z * v.z + v.w * v.w);
  }
  for (int o = 32; o > 0; o >>= 1) {
    s  += __shfl_down(s, o);
    ss += __shfl_down(ss, o);
  }
  __shared__ float rs_[4], rss_[4];
  int wid = t >> 6, lane = t & 63;
  if (lane == 0) { rs_[wid] = s; rss_[wid] = ss; }
  __syncthreads();
  if (t == 0) {
    float stot  = rs_[0] + rs_[1] + rs_[2] + rs_[3];
    float sstot = rss_[0] + rss_[1] + rss_[2] + rss_[3];
    float mean = stot / (float)n;
    float var  = sstot / (float)n - mean * mean;
    stats[bg] = make_float2(mean, rsqrtf(var + EPSV));
  }
}

// ---------------------------------------------------------------------------
// Kernel 1b: normalize + transpose -> ht[b][seq][ch] bf16.
// ---------------------------------------------------------------------------
__global__ __launch_bounds__(256) void gn_apply(
    const float* __restrict__ x, const float2* __restrict__ stats,
    const float* __restrict__ gamma, const float* __restrict__ beta,
    short* __restrict__ ht) {
  __shared__ float Ls[64 * 65];
  int s0 = blockIdx.x * 64, ch0 = blockIdx.y * 64, b = blockIdx.z;
  int t = threadIdx.x;

  for (int i = 0; i < 4; i++) {
    int lin = t + i * 256;           // 64 rows x 16 float4
    int r = lin >> 4, c4 = lin & 15;
    int ch = ch0 + r;
    float2 st = stats[b * NG + (ch >> 4)];
    float ga = gamma[ch] * st.y;     // fold rsig into gamma
    float be = beta[ch] - st.x * ga;
    float4 v = *reinterpret_cast<const float4*>(
        x + ((size_t)(b * C_ + ch)) * HW_ + s0 + c4 * 4);
    Ls[r * 65 + c4 * 4 + 0] = v.x * ga + be;
    Ls[r * 65 + c4 * 4 + 1] = v.y * ga + be;
    Ls[r * 65 + c4 * 4 + 2] = v.z * ga + be;
    Ls[r * 65 + c4 * 4 + 3] = v.w * ga + be;
  }
  __syncthreads();
  for (int i = 0; i < 4; i++) {
    int lin = t + i * 256;           // 64 seq x 16 short4
    int sq = lin >> 4, cq = lin & 15;
    float a0 = Ls[(cq * 4 + 0) * 65 + sq];
    float a1 = Ls[(cq * 4 + 1) * 65 + sq];
    float a2 = Ls[(cq * 4 + 2) * 65 + sq];
    float a3 = Ls[(cq * 4 + 3) * 65 + sq];
    *reinterpret_cast<short4v*>(
        ht + ((size_t)b * 1024 + s0 + sq) * 512 + ch0 + cq * 4) =
        pack4(a0, a1, a2, a3);
  }
}

// ---------------------------------------------------------------------------
// Kernel 2: QKV GEMM, m97 structure (guide §5, measured 874 TF at this tile):
//   128x128 tile, BK=32, double-buffered LDS staged via global_load_lds
//   dwordx4 (4 issues/K-step), one barrier per K-step, ds_read_b128 frags.
//   Replaces per-wave direct global loads (2x redundant L2 traffic +
//   latency-exposed).  Epilogue identical to the proven r0/r3 version.
// ---------------------------------------------------------------------------
__global__ __launch_bounds__(256) void gemm_qkv(
    const short* __restrict__ Wb, const short* __restrict__ ht,
    const float* __restrict__ bias,
    short* __restrict__ Qt, short* __restrict__ Kt, short* __restrict__ Vn) {
  __shared__ short As[2][4096];   // [buf][row*32 + k]  128 rows x 32 k
  __shared__ short Bs[2][4096];
  int bx = blockIdx.x, by = blockIdx.y, bb = blockIdx.z;
  int m0 = by * 128, n0 = bx * 128;
  int t = threadIdx.x;
  int w = t >> 6, lane = t & 63, n16 = lane & 15, quad = lane >> 4;
  int wm = (w >> 1) * 64, wn = (w & 1) * 64;

  // staging sources: thread t covers row t>>2 (+64 for 2nd issue), 16B chunk t&3
  const short* Wa = Wb + (size_t)(m0 + (t >> 2)) * 512 + (t & 3) * 8;
  const short* Xa = ht + (size_t)bb * 1024 * 512 +
                    (size_t)(n0 + (t >> 2)) * 512 + (t & 3) * 8;

#define STAGE(buf, kk)                                                \
  do {                                                                \
    glds16(Wa + (kk), &As[buf][t * 8]);                               \
    glds16(Wa + 64 * 512 + (kk), &As[buf][2048 + t * 8]);             \
    glds16(Xa + (kk), &Bs[buf][t * 8]);                               \
    glds16(Xa + 64 * 512 + (kk), &Bs[buf][2048 + t * 8]);             \
  } while (0)

  floatx4 acc[4][4];
  for (int i = 0; i < 4; i++)
    for (int j = 0; j < 4; j++) acc[i][j] = (floatx4){0.f, 0.f, 0.f, 0.f};

  STAGE(0, 0);
#pragma unroll 1
  for (int ks = 0; ks < 16; ks++) {
    int cur = ks & 1;
    __syncthreads();                       // drains staging + prior ds_reads
    if (ks < 15) STAGE(cur ^ 1, (ks + 1) * 32);
    short8 a[4], b[4];
    for (int im = 0; im < 4; im++)
      a[im] = *reinterpret_cast<const short8*>(
          &As[cur][(wm + im * 16 + n16) * 32 + quad * 8]);
    for (int in = 0; in < 4; in++)
      b[in] = *reinterpret_cast<const short8*>(
          &Bs[cur][(wn + in * 16 + n16) * 32 + quad * 8]);
    for (int im = 0; im < 4; im++)
      for (int in = 0; in < 4; in++)
        acc[im][in] = MFMA(a[im], b[in], acc[im][in]);
  }
#undef STAGE

  if (m0 < 1024) {                 // Q or K: transposed store [seq][d]
    const bool isQ = (m0 < 512);
    short* base = isQ ? Qt : Kt;
    const float sc = isQ ? 0.125f : 1.0f;   // fold 1/sqrt(64) into Q
    for (int im = 0; im < 4; im++) {
      int m = m0 + wm + im * 16 + quad * 4;
      int hh = (m >> 6) & 7, d0 = m & 63;
      float4 bi = *reinterpret_cast<const float4*>(&bias[m]);
      short* hb = base + (size_t)(bb * 8 + hh) * 1024 * 64 + d0;
      for (int in = 0; in < 4; in++) {
        int nn = n0 + wn + in * 16 + n16;
        *reinterpret_cast<short4v*>(hb + (size_t)nn * 64) =
            pack4((acc[im][in][0] + bi.x) * sc, (acc[im][in][1] + bi.y) * sc,
                  (acc[im][in][2] + bi.z) * sc, (acc[im][in][3] + bi.w) * sc);
      }
    }
  } else {                         // V: natural store [ch][seq]
    for (int im = 0; im < 4; im++) {
      int m = m0 + wm + im * 16 + quad * 4;
      float4 bi = *reinterpret_cast<const float4*>(&bias[m]);
      int ch = m - 1024;
      for (int in = 0; in < 4; in++) {
        int nn = n0 + wn + in * 16 + n16;
        short* vp = Vn + (size_t)(bb * 512 + ch) * 1024 + nn;
        vp[0]    = f2bs(acc[im][in][0] + bi.x);
        vp[1024] = f2bs(acc[im][in][1] + bi.y);
        vp[2048] = f2bs(acc[im][in][2] + bi.z);
        vp[3072] = f2bs(acc[im][in][3] + bi.w);
      }
    }
  }
}

// ---------------------------------------------------------------------------
// Kernel 3: barrier-free MFMA attention — EXACT r3-benched version (66.8 us).
// ---------------------------------------------------------------------------
__global__ __launch_bounds__(256, 2) void attn_mfma(
    const short* __restrict__ Qt, const short* __restrict__ Kt,
    const short* __restrict__ Vn, short* __restrict__ attnT) {
  __shared__ short Ps[4][2][2][1024];   // [wave][kt&1][qt][16*64]  32 KB
  int blk0 = blockIdx.x;
  int blk = (blk0 & 7) * 64 + (blk0 >> 3);   // 512 = 8 XCD x 64: batch->XCD
  int qb = blk & 7, h = (blk >> 3) & 7, b = blk >> 6;
  int t = threadIdx.x;
  int w = t >> 6, lane = t & 63, n16 = lane & 15, quad = lane >> 4;
  int q0 = qb * 128 + w * 32;

  const short* Qp = Qt + (size_t)(b * 8 + h) * 1024 * 64;
  const short* Kp = Kt + (size_t)(b * 8 + h) * 1024 * 64;
  const short* Vp = Vn + (size_t)(b * 512 + h * 64) * 1024;

  short8 qa[2][2];
  for (int qt = 0; qt < 2; qt++)
    for (int f = 0; f < 2; f++)
      qa[qt][f] = *reinterpret_cast<const short8*>(
          Qp + (size_t)(q0 + qt * 16 + n16) * 64 + f * 32 + quad * 8);

  floatx4 O[2][4];
  float l[2][4];
  for (int qt = 0; qt < 2; qt++)
    for (int i = 0; i < 4; i++) {
      O[qt][i] = (floatx4){0.f, 0.f, 0.f, 0.f};
      l[qt][i] = 0.f;
    }

#define LOADK(dst, ktv)                                                      \
  do {                                                                       \
    int k0_ = (ktv) * 64;                                                    \
    for (int nt_ = 0; nt_ < 4; nt_++)                                        \
      for (int f_ = 0; f_ < 2; f_++)                                         \
        dst[nt_][f_] = *reinterpret_cast<const short8*>(                     \
            Kp + (size_t)(k0_ + nt_ * 16 + n16) * 64 + f_ * 32 + quad * 8);  \
  } while (0)

#define BODY(kf, ktv)                                                        \
  do {                                                                       \
    int k0_ = (ktv) * 64;                                                    \
    floatx4 S0_[4], S1_[4];                                                  \
    for (int nt_ = 0; nt_ < 4; nt_++) {                                      \
      floatx4 sa_ = (floatx4){0.f, 0.f, 0.f, 0.f};                           \
      sa_ = MFMA(qa[0][0], kf[nt_][0], sa_);                                 \
      S0_[nt_] = MFMA(qa[0][1], kf[nt_][1], sa_);                            \
    }                                                                        \
    for (int nt_ = 0; nt_ < 4; nt_++) {                                      \
      floatx4 sa_ = (floatx4){0.f, 0.f, 0.f, 0.f};                           \
      sa_ = MFMA(qa[1][0], kf[nt_][0], sa_);                                 \
      S1_[nt_] = MFMA(qa[1][1], kf[nt_][1], sa_);                            \
    }                                                                        \
    /* V for this kt: issue now, consume after softmax (L2 lat hidden) */    \
    short8 v_[4][2];                                                         \
    for (int nd_ = 0; nd_ < 4; nd_++) {                                      \
      const short* vs_ =                                                     \
          Vp + (size_t)(nd_ * 16 + n16) * 1024 + k0_ + quad * 8;             \
      v_[nd_][0] = *reinterpret_cast<const short8*>(vs_);                    \
      v_[nd_][1] = *reinterpret_cast<const short8*>(vs_ + 32);               \
    }                                                                        \
    short* Pb_ = &Ps[w][(ktv) & 1][0][0];                                    \
    int sub_ = n16 & 7, hi_ = n16 >> 3;                                      \
    for (int r_ = 0; r_ < 4; r_++) {                                         \
      int row_ = quad * 4 + r_;                                              \
      float p0_ = __expf(S0_[0][r_]);                                        \
      float p1_ = __expf(S0_[1][r_]);                                        \
      float p2_ = __expf(S0_[2][r_]);                                        \
      float p3_ = __expf(S0_[3][r_]);                                        \
      l[0][r_] += (p0_ + p1_) + (p2_ + p3_);                                 \
      Pb_[row_ * 64 + ((0 + hi_ + row_) & 7) * 8 + sub_] = f2bs(p0_);        \
      Pb_[row_ * 64 + ((2 + hi_ + row_) & 7) * 8 + sub_] = f2bs(p1_);        \
      Pb_[row_ * 64 + ((4 + hi_ + row_) & 7) * 8 + sub_] = f2bs(p2_);        \
      Pb_[row_ * 64 + ((6 + hi_ + row_) & 7) * 8 + sub_] = f2bs(p3_);        \
    }                                                                        \
    for (int r_ = 0; r_ < 4; r_++) {                                         \
      int row_ = quad * 4 + r_;                                              \
      float p0_ = __expf(S1_[0][r_]);                                        \
      float p1_ = __expf(S1_[1][r_]);                                        \
      float p2_ = __expf(S1_[2][r_]);                                        \
      float p3_ = __expf(S1_[3][r_]);                                        \
      l[1][r_] += (p0_ + p1_) + (p2_ + p3_);                                 \
      Pb_[1024 + row_ * 64 + ((0 + hi_ + row_) & 7) * 8 + sub_] = f2bs(p0_); \
      Pb_[1024 + row_ * 64 + ((2 + hi_ + row_) & 7) * 8 + sub_] = f2bs(p1_); \
      Pb_[1024 + row_ * 64 + ((4 + hi_ + row_) & 7) * 8 + sub_] = f2bs(p2_); \
      Pb_[1024 + row_ * 64 + ((6 + hi_ + row_) & 7) * 8 + sub_] = f2bs(p3_); \
    }                                                                        \
    short8 pa0_[2], pa1_[2];                                                 \
    for (int f_ = 0; f_ < 2; f_++) {                                         \
      pa0_[f_] = *reinterpret_cast<const short8*>(                           \
          Pb_ + n16 * 64 + ((quad + 4 * f_ + n16) & 7) * 8);                 \
      pa1_[f_] = *reinterpret_cast<const short8*>(                           \
          Pb_ + 1024 + n16 * 64 + ((quad + 4 * f_ + n16) & 7) * 8);          \
    }                                                                        \
    __builtin_amdgcn_s_setprio(1);                                           \
    for (int nd_ = 0; nd_ < 4; nd_++) {                                      \
      O[0][nd_] = MFMA(pa0_[0], v_[nd_][0], O[0][nd_]);                      \
      O[0][nd_] = MFMA(pa0_[1], v_[nd_][1], O[0][nd_]);                      \
      O[1][nd_] = MFMA(pa1_[0], v_[nd_][0], O[1][nd_]);                      \
      O[1][nd_] = MFMA(pa1_[1], v_[nd_][1], O[1][nd_]);                      \
    }                                                                        \
    __builtin_amdgcn_s_setprio(0);                                           \
  } while (0)

  short8 kfA[4][2], kfB[4][2];
  LOADK(kfA, 0);
#pragma unroll 1
  for (int kt = 0; kt < 16; kt += 2) {
    LOADK(kfB, kt + 1);
    BODY(kfA, kt);
    if (kt + 2 < 16) LOADK(kfA, kt + 2);
    BODY(kfB, kt + 1);
  }
#undef LOADK
#undef BODY

  // epilogue: reduce l across the 16-lane row group, write [seq][ch] bf16
  for (int qt = 0; qt < 2; qt++)
    for (int r = 0; r < 4; r++) {
      float s = l[qt][r];
      s += __shfl_xor(s, 1);
      s += __shfl_xor(s, 2);
      s += __shfl_xor(s, 4);
      s += __shfl_xor(s, 8);
      l[qt][r] = 1.0f / s;
    }
  for (int qt = 0; qt < 2; qt++)
    for (int nd = 0; nd < 4; nd++)
      for (int r = 0; r < 4; r++) {
        int q = q0 + qt * 16 + quad * 4 + r;
        int ch = h * 64 + nd * 16 + n16;
        attnT[((size_t)b * 1024 + q) * 512 + ch] = f2bs(O[qt][nd][r] * l[qt][r]);
      }
}

// ---------------------------------------------------------------------------
// Kernel 4: projection GEMM, m97 structure (same staging as gemm_qkv) +
// bias + residual, fp32 out.  Epilogue identical to the proven version.
// ---------------------------------------------------------------------------
__global__ __launch_bounds__(256) void gemm_out(
    const short* __restrict__ Wb, const short* __restrict__ Xt,
    const float* __restrict__ bias, const float* __restrict__ resid,
    float* __restrict__ out) {
  __shared__ short As[2][4096];
  __shared__ short Bs[2][4096];
  int bx = blockIdx.x, by = blockIdx.y, bb = blockIdx.z;
  int m0 = by * 128, n0 = bx * 128;
  int t = threadIdx.x;
  int w = t >> 6, lane = t & 63, n16 = lane & 15, quad = lane >> 4;
  int wm = (w >> 1) * 64, wn = (w & 1) * 64;

  const short* Wa = Wb + (size_t)(m0 + (t >> 2)) * 512 + (t & 3) * 8;
  const short* Xa = Xt + (size_t)bb * 1024 * 512 +
                    (size_t)(n0 + (t >> 2)) * 512 + (t & 3) * 8;

#define STAGE(buf, kk)                                                \
  do {                                                                \
    glds16(Wa + (kk), &As[buf][t * 8]);                               \
    glds16(Wa + 64 * 512 + (kk), &As[buf][2048 + t * 8]);             \
    glds16(Xa + (kk), &Bs[buf][t * 8]);                               \
    glds16(Xa + 64 * 512 + (kk), &Bs[buf][2048 + t * 8]);             \
  } while (0)

  floatx4 acc[4][4];
  for (int i = 0; i < 4; i++)
    for (int j = 0; j < 4; j++) acc[i][j] = (floatx4){0.f, 0.f, 0.f, 0.f};

  STAGE(0, 0);
#pragma unroll 1
  for (int ks = 0; ks < 16; ks++) {
    int cur = ks & 1;
    __syncthreads();
    if (ks < 15) STAGE(cur ^ 1, (ks + 1) * 32);
    short8 a[4], b[4];
    for (int im = 0; im < 4; im++)
      a[im] = *reinterpret_cast<const short8*>(
          &As[cur][(wm + im * 16 + n16) * 32 + quad * 8]);
    for (int in = 0; in < 4; in++)
      b[in] = *reinterpret_cast<const short8*>(
          &Bs[cur][(wn + in * 16 + n16) * 32 + quad * 8]);
    for (int im = 0; im < 4; im++)
      for (int in = 0; in < 4; in++)
        acc[im][in] = MFMA(a[im], b[in], acc[im][in]);
  }
#undef STAGE

  for (int im = 0; im < 4; im++) {
    int m = m0 + wm + im * 16 + quad * 4;
    float4 bi = *reinterpret_cast<const float4*>(&bias[m]);
    for (int in = 0; in < 4; in++) {
      int nn = n0 + wn + in * 16 + n16;
      size_t idx = ((size_t)bb * 512 + m) * 1024 + nn;
      out[idx]        = acc[im][in][0] + bi.x + resid[idx];
      out[idx + 1024] = acc[im][in][1] + bi.y + resid[idx + 1024];
      out[idx + 2048] = acc[im][in][2] + bi.z + resid[idx + 2048];
      out[idx + 3072] = acc[im][in][3] + bi.w + resid[idx + 3072];
    }
  }
}

// ---------------------------------------------------------------------------
extern "C" void kernel_launch(void* const* d_in, const int* in_sizes, int n_in,
                              void* d_out, int out_size, void* d_ws, size_t ws_size,
                              hipStream_t stream) {
  const float* x     = (const float*)d_in[0];
  const float* gamma = (const float*)d_in[1];
  const float* beta  = (const float*)d_in[2];
  const float* w_in  = (const float*)d_in[3];
  const float* b_in  = (const float*)d_in[4];
  const float* w_out = (const float*)d_in[5];
  const float* b_out = (const float*)d_in[6];
  float* out = (float*)d_out;

  char* ws = (char*)d_ws;
  short* ht    = (short*)ws;                    //  8 MiB [8][1024][512]
  short* Qt    = (short*)(ws + (8u  << 20));    //  8 MiB [64][1024][64]
  short* Kt    = (short*)(ws + (16u << 20));    //  8 MiB [64][1024][64]
  short* Vn    = (short*)(ws + (24u << 20));    //  8 MiB [8][512][1024]
  short* attnT = (short*)(ws + (32u << 20));    //  8 MiB [8][1024][512]
  short* wbf1  = (short*)(ws + (40u << 20));    //  1.5 MiB
  short* wbf2  = (short*)(ws + (42u << 20));    //  0.5 MiB
  float2* stats = (float2*)(ws + (44u << 20));  //  2 KiB [256]

  cast2_f2b<<<1024, 256, 0, stream>>>(w_in, wbf1, w_out, wbf2);
  gn_stats<<<B_ * NG, 256, 0, stream>>>(x, stats);
  gn_apply<<<dim3(16, 8, B_), 256, 0, stream>>>(x, stats, gamma, beta, ht);
  gemm_qkv<<<dim3(8, 12, B_), 256, 0, stream>>>(wbf1, ht, b_in, Qt, Kt, Vn);
  attn_mfma<<<B_ * 8 * 8, 256, 0, stream>>>(Qt, Kt, Vn, attnT);
  gemm_out<<<dim3(8, 4, B_), 256, 0, stream>>>(wbf2, attnT, b_out, x, out);
}